// Round 3
// baseline (639.175 us; speedup 1.0000x reference)
//
#include <hip/hip_runtime.h>
#include <math.h>

#define HH 80
#define WW 80
#define NPIX 6400
#define LL 21
#define NITER 5
#define TJ 256              // j-tile per block for bilateral kernel
#define JB (NPIX / TJ)      // 25 j-chunks
#define C_LOG2E 1.44269504088896f

// ---------------- pre: feat [5][N] (rgb centered), mhs[N] = -0.5*log2e*|f|^2,
//                  nsp (reciprocal spatial norm), zero nbacc
__global__ void k_pre(const float* __restrict__ img, float* __restrict__ feat,
                      float* __restrict__ mhs, float* __restrict__ nsp,
                      float* __restrict__ nbacc) {
    int i = blockIdx.x * blockDim.x + threadIdx.x;
    if (i >= NPIX) return;
    float x = (float)(i % WW), y = (float)(i / WW);
    float f0 = x * (1.0f / 160.0f);
    float f1 = y * (1.0f / 160.0f);
    // centering is exact w.r.t. the math: K depends only on feature DIFFS.
    float f2 = (img[0 * NPIX + i] - 127.5f) * (1.0f / 3.0f);
    float f3 = (img[1 * NPIX + i] - 127.5f) * (1.0f / 3.0f);
    float f4 = (img[2 * NPIX + i] - 127.5f) * (1.0f / 3.0f);
    feat[0 * NPIX + i] = f0;
    feat[1 * NPIX + i] = f1;
    feat[2 * NPIX + i] = f2;
    feat[3 * NPIX + i] = f3;
    feat[4 * NPIX + i] = f4;
    float s = f0 * f0 + f1 * f1 + f2 * f2 + f3 * f3 + f4 * f4;
    mhs[i] = -0.5f * C_LOG2E * s;
    float sx = 0.f, sy = 0.f;
    for (int t = 0; t < WW; t++) { float d = x - (float)t; sx += __expf(-d * d * (1.0f / 18.0f)); }
    for (int t = 0; t < HH; t++) { float d = y - (float)t; sy += __expf(-d * d * (1.0f / 18.0f)); }
    nsp[i] = 1.0f / (sx * sy + 1e-8f);
    nbacc[i] = 0.f;
}

// ---------------- M1 = C @ Wsp, M2 = C @ Wbi  (21x21 each)
__global__ void k_mats(const float* __restrict__ Wsp, const float* __restrict__ Wbi,
                       const float* __restrict__ C, float* __restrict__ M1,
                       float* __restrict__ M2) {
    int t = threadIdx.x;
    if (t >= LL * LL) return;
    int l = t / LL, k = t % LL;
    float a = 0.f, b = 0.f;
    for (int m = 0; m < LL; m++) {
        a += C[l * LL + m] * Wsp[m * LL + k];
        b += C[l * LL + m] * Wbi[m * LL + k];
    }
    M1[t] = a; M2[t] = b;
}

// ---------------- initial softmax over labels + zero bi accumulator
__global__ void k_sm0(const float* __restrict__ in, float* __restrict__ q,
                      float* __restrict__ bi) {
    int i = blockIdx.x * blockDim.x + threadIdx.x;
    if (i >= NPIX) return;
    float v[LL];
    float m = -1e30f;
    for (int l = 0; l < LL; l++) { v[l] = in[l * NPIX + i]; m = fmaxf(m, v[l]); }
    float s = 0.f;
    for (int l = 0; l < LL; l++) { v[l] = __expf(v[l] - m); s += v[l]; }
    float r = 1.0f / s;
    for (int l = 0; l < LL; l++) {
        q[l * NPIX + i] = v[l] * r;
        bi[l * NPIX + i] = 0.f;
    }
}

// ---------------- fused separable spatial filter: one block per label plane
__global__ void k_spat(const float* __restrict__ q, float* __restrict__ sp) {
    __shared__ float buf1[HH][WW + 1];
    __shared__ float buf2[HH][WW + 1];
    __shared__ float g[WW];
    int l = blockIdx.x;
    int t = threadIdx.x;          // 0..639
    if (t < WW) g[t] = __expf(-(float)(t * t) * (1.0f / 18.0f));
#pragma unroll
    for (int k = 0; k < 10; k++) {
        int p = t + k * 640;
        buf1[p / WW][p % WW] = q[l * NPIX + p];
    }
    __syncthreads();
#pragma unroll
    for (int k = 0; k < 10; k++) {
        int p = t + k * 640;
        int y = p / WW, x = p % WW;
        float s = 0.f;
        for (int xp = 0; xp < WW; xp++) {
            int d = x - xp; d = d < 0 ? -d : d;
            s += g[d] * buf1[y][xp];
        }
        buf2[y][x] = s;
    }
    __syncthreads();
#pragma unroll
    for (int k = 0; k < 10; k++) {
        int p = t + k * 640;
        int y = p / WW, x = p % WW;
        float s = 0.f;
        for (int yp = 0; yp < HH; yp++) {
            int d = y - yp; d = d < 0 ? -d : d;
            s += g[d] * buf2[yp][x];
        }
        sp[l * NPIX + p] = s;
    }
}

// ---------------- bilateral message passing, log-domain single-exp form:
// K_ij = exp2( log2e*(fi.fj) + mhs_i + mhs_j );  bi[l,i] += sum_j K_ij q[l,j]
// NORM: also accumulate nbacc[i] += sum_j K_ij  (iteration 0 only)
template <bool NORM>
__global__ void k_bilat(const float* __restrict__ feat, const float* __restrict__ mhs,
                        const float* __restrict__ q, float* __restrict__ bi,
                        float* __restrict__ nbacc) {
    // row: [f0..f3][f4, mhs_j, q20, 0][q0..q19]  -> 28 floats, 7x b128 reads
    __shared__ float tile[TJ][28];
    int tid = threadIdx.x;        // 0..127
    int j0 = blockIdx.y * TJ;
    for (int r = tid; r < TJ; r += 128) {
        int j = j0 + r;
        float4 v0, v1;
        v0.x = feat[0 * NPIX + j]; v0.y = feat[1 * NPIX + j];
        v0.z = feat[2 * NPIX + j]; v0.w = feat[3 * NPIX + j];
        v1.x = feat[4 * NPIX + j]; v1.y = mhs[j];
        v1.z = q[20 * NPIX + j];   v1.w = 0.f;
        *(float4*)&tile[r][0] = v0;
        *(float4*)&tile[r][4] = v1;
#pragma unroll
        for (int l = 0; l < 20; l += 4) {
            float4 t4;
            t4.x = q[(l + 0) * NPIX + j]; t4.y = q[(l + 1) * NPIX + j];
            t4.z = q[(l + 2) * NPIX + j]; t4.w = q[(l + 3) * NPIX + j];
            *(float4*)&tile[r][8 + l] = t4;
        }
    }
    int i0 = blockIdx.x * 256 + tid;   // px0
    int i1 = i0 + 128;                 // px1
    float fA0 = feat[0 * NPIX + i0] * C_LOG2E, fB0 = feat[0 * NPIX + i1] * C_LOG2E;
    float fA1 = feat[1 * NPIX + i0] * C_LOG2E, fB1 = feat[1 * NPIX + i1] * C_LOG2E;
    float fA2 = feat[2 * NPIX + i0] * C_LOG2E, fB2 = feat[2 * NPIX + i1] * C_LOG2E;
    float fA3 = feat[3 * NPIX + i0] * C_LOG2E, fB3 = feat[3 * NPIX + i1] * C_LOG2E;
    float fA4 = feat[4 * NPIX + i0] * C_LOG2E, fB4 = feat[4 * NPIX + i1] * C_LOG2E;
    float sA = mhs[i0], sB = mhs[i1];
    __syncthreads();
    float accA[LL], accB[LL];
#pragma unroll
    for (int l = 0; l < LL; l++) { accA[l] = 0.f; accB[l] = 0.f; }
    float nA = 0.f, nB = 0.f;
#pragma unroll 4
    for (int jj = 0; jj < TJ; jj++) {
        const float* r = &tile[jj][0];
        float4 f03 = *(const float4*)(r + 0);
        float4 f4m = *(const float4*)(r + 4);
        float qv[LL];
        *(float4*)&qv[0]  = *(const float4*)(r + 8);
        *(float4*)&qv[4]  = *(const float4*)(r + 12);
        *(float4*)&qv[8]  = *(const float4*)(r + 16);
        *(float4*)&qv[12] = *(const float4*)(r + 20);
        *(float4*)&qv[16] = *(const float4*)(r + 24);
        qv[20] = f4m.z;
        float dA = sA + f4m.y;
        float dB = sB + f4m.y;
        dA = fmaf(fA0, f03.x, dA); dB = fmaf(fB0, f03.x, dB);
        dA = fmaf(fA1, f03.y, dA); dB = fmaf(fB1, f03.y, dB);
        dA = fmaf(fA2, f03.z, dA); dB = fmaf(fB2, f03.z, dB);
        dA = fmaf(fA3, f03.w, dA); dB = fmaf(fB3, f03.w, dB);
        dA = fmaf(fA4, f4m.x, dA); dB = fmaf(fB4, f4m.x, dB);
        float eA = exp2f(dA);
        float eB = exp2f(dB);
        if (NORM) { nA += eA; nB += eB; }
#pragma unroll
        for (int l = 0; l < LL; l++) accA[l] = fmaf(eA, qv[l], accA[l]);
#pragma unroll
        for (int l = 0; l < LL; l++) accB[l] = fmaf(eB, qv[l], accB[l]);
    }
#pragma unroll
    for (int l = 0; l < LL; l++) {
        atomicAdd(&bi[l * NPIX + i0], accA[l]);
        atomicAdd(&bi[l * NPIX + i1], accB[l]);
    }
    if (NORM) {
        atomicAdd(&nbacc[i0], nA);
        atomicAdd(&nbacc[i1], nB);
    }
}

// ---------------- combine (+ fused softmax for non-final iters):
// a = unary + M1 @ (sp*nsp) + M2 @ (bi*nbi);  last ? out=a : (q=softmax(a), bi=0)
__global__ void k_comb(const float* __restrict__ unary, const float* __restrict__ sp,
                       float* __restrict__ bi, const float* __restrict__ nsp,
                       const float* __restrict__ nbacc, const float* __restrict__ M1,
                       const float* __restrict__ M2, float* __restrict__ qout,
                       float* __restrict__ out, int last) {
    __shared__ float m1s[LL * 24];
    __shared__ float m2s[LL * 24];
    int tid = threadIdx.x;
    for (int t = tid; t < LL * LL; t += blockDim.x) {
        int l = t / LL, k = t % LL;
        m1s[l * 24 + k] = M1[t];
        m2s[l * 24 + k] = M2[t];
    }
    __syncthreads();
    int i = blockIdx.x * blockDim.x + tid;
    if (i >= NPIX) return;
    float ns = nsp[i];
    float nb = 1.0f / (nbacc[i] + 1e-8f);
    float sv[LL], bv[LL];
    for (int k = 0; k < LL; k++) {
        sv[k] = sp[k * NPIX + i] * ns;
        bv[k] = bi[k * NPIX + i] * nb;
    }
    float a[LL];
    for (int l = 0; l < LL; l++) {
        float acc = unary[l * NPIX + i];
        const float* r1 = &m1s[l * 24];
        const float* r2 = &m2s[l * 24];
#pragma unroll
        for (int k = 0; k < LL; k++) acc += r1[k] * sv[k] + r2[k] * bv[k];
        a[l] = acc;
    }
    if (last) {
        for (int l = 0; l < LL; l++) out[l * NPIX + i] = a[l];
    } else {
        float m = -1e30f;
        for (int l = 0; l < LL; l++) m = fmaxf(m, a[l]);
        float s = 0.f;
        for (int l = 0; l < LL; l++) { a[l] = __expf(a[l] - m); s += a[l]; }
        float r = 1.0f / s;
        for (int l = 0; l < LL; l++) {
            qout[l * NPIX + i] = a[l] * r;
            bi[l * NPIX + i] = 0.f;
        }
    }
}

extern "C" void kernel_launch(void* const* d_in, const int* in_sizes, int n_in,
                              void* d_out, int out_size, void* d_ws, size_t ws_size,
                              hipStream_t stream) {
    const float* img   = (const float*)d_in[0];  // [3][N]
    const float* unary = (const float*)d_in[1];  // [L][N]
    const float* Wsp   = (const float*)d_in[2];  // [L][L]
    const float* Wbi   = (const float*)d_in[3];  // [L][L]
    const float* C     = (const float*)d_in[4];  // [L][L]
    float* out = (float*)d_out;                  // [L][N]

    const int LN = LL * NPIX;
    float* w = (float*)d_ws;
    float* q     = w;              w += LN;
    float* sp    = w;              w += LN;
    float* bi    = w;              w += LN;
    float* feat  = w;              w += 5 * NPIX;
    float* mhs   = w;              w += NPIX;
    float* nsp   = w;              w += NPIX;
    float* nbacc = w;              w += NPIX;
    float* M1    = w;              w += LL * LL;
    float* M2    = w;              w += LL * LL;

    k_pre<<<JB, TJ, 0, stream>>>(img, feat, mhs, nsp, nbacc);
    k_mats<<<1, 512, 0, stream>>>(Wsp, Wbi, C, M1, M2);
    k_sm0<<<JB, TJ, 0, stream>>>(unary, q, bi);

    for (int it = 0; it < NITER; it++) {
        int last = (it == NITER - 1);
        k_spat<<<LL, 640, 0, stream>>>(q, sp);
        if (it == 0)
            k_bilat<true><<<dim3(JB, JB), 128, 0, stream>>>(feat, mhs, q, bi, nbacc);
        else
            k_bilat<false><<<dim3(JB, JB), 128, 0, stream>>>(feat, mhs, q, bi, nbacc);
        k_comb<<<JB, TJ, 0, stream>>>(unary, sp, bi, nsp, nbacc, M1, M2, q, out, last);
    }
}

// Round 5
// 296.541 us; speedup vs baseline: 2.1554x; 2.1554x over previous
//
#include <hip/hip_runtime.h>
#include <hip/hip_bf16.h>
#include <math.h>

#define HH 80
#define WW 80
#define NPIX 6400
#define LL 21
#define NITER 5
#define C_LOG2E 1.44269504088896f

// bilateral MFMA kernel geometry
#define SJ  320             // j-slice per block
#define CHK (SJ / 32)       // 10 chunks of 32 j
#define QROW 164            // Q LDS row stride in u32 (320 bf16 + pad, 656 B)

typedef short short8 __attribute__((ext_vector_type(8)));
typedef float f32x16 __attribute__((ext_vector_type(16)));

__device__ inline ushort bf_rne(float x) {
    uint u = __float_as_uint(x);
    return (ushort)((u + 0x7FFFu + ((u >> 16) & 1u)) >> 16);
}
__device__ inline float bf_to_f(ushort h) { return __uint_as_float(((uint)h) << 16); }
__device__ inline uint pk2(float a, float b) {
    __hip_bfloat162 t = __float22bfloat162_rn(make_float2(a, b));
    return *reinterpret_cast<uint*>(&t);
}
__device__ inline f32x16 zero16() {
    f32x16 v;
#pragma unroll
    for (int k = 0; k < 16; k++) v[k] = 0.f;
    return v;
}

// ---------------- pre: feat [5][N] f32 (rgb centered), Fj A-rows [N][16 bf16],
// mhs[N] = -0.5*log2e*|f|^2, nsp.
// A-row k-slot layout (pairs with B-row in k_bilat so rgb product is EXACT):
//   [h0,h1,h2,h3,h4, l2,l3,l4, h2,h3,h4, l2,l3,l4, 0,0]
__global__ void k_pre(const float* __restrict__ img, float* __restrict__ feat,
                      ushort* __restrict__ fjg, float* __restrict__ mhs,
                      float* __restrict__ nsp) {
    int i = blockIdx.x * blockDim.x + threadIdx.x;
    if (i >= NPIX) return;
    float x = (float)(i % WW), y = (float)(i / WW);
    float f[5];
    f[0] = x * (1.0f / 160.0f);
    f[1] = y * (1.0f / 160.0f);
    f[2] = (img[0 * NPIX + i] - 127.5f) * (1.0f / 3.0f);
    f[3] = (img[1 * NPIX + i] - 127.5f) * (1.0f / 3.0f);
    f[4] = (img[2 * NPIX + i] - 127.5f) * (1.0f / 3.0f);
    float s = 0.f;
    ushort hi[5], lo[5];
#pragma unroll
    for (int c = 0; c < 5; c++) {
        feat[c * NPIX + i] = f[c];
        s += f[c] * f[c];
        hi[c] = bf_rne(f[c]);
        lo[c] = bf_rne(f[c] - bf_to_f(hi[c]));
    }
    mhs[i] = -0.5f * C_LOG2E * s;
    ushort row[16];
    row[0] = hi[0]; row[1] = hi[1]; row[2] = hi[2]; row[3] = hi[3]; row[4] = hi[4];
    row[5] = lo[2]; row[6] = lo[3]; row[7] = lo[4];
    row[8] = hi[2]; row[9] = hi[3]; row[10] = hi[4];
    row[11] = lo[2]; row[12] = lo[3]; row[13] = lo[4];
    row[14] = 0; row[15] = 0;
    uint4 w0, w1;
    w0.x = (uint)row[0] | ((uint)row[1] << 16);
    w0.y = (uint)row[2] | ((uint)row[3] << 16);
    w0.z = (uint)row[4] | ((uint)row[5] << 16);
    w0.w = (uint)row[6] | ((uint)row[7] << 16);
    w1.x = (uint)row[8] | ((uint)row[9] << 16);
    w1.y = (uint)row[10] | ((uint)row[11] << 16);
    w1.z = (uint)row[12] | ((uint)row[13] << 16);
    w1.w = 0;
    *(uint4*)(fjg + i * 16) = w0;
    *(uint4*)(fjg + i * 16 + 8) = w1;
    float sx = 0.f, sy = 0.f;
    for (int t = 0; t < WW; t++) { float d = x - (float)t; sx += __expf(-d * d * (1.0f / 18.0f)); }
    for (int t = 0; t < HH; t++) { float d = y - (float)t; sy += __expf(-d * d * (1.0f / 18.0f)); }
    nsp[i] = 1.0f / (sx * sy + 1e-8f);
}

// ---------------- M1 = C @ Wsp, M2 = C @ Wbi
__global__ void k_mats(const float* __restrict__ Wsp, const float* __restrict__ Wbi,
                       const float* __restrict__ C, float* __restrict__ M1,
                       float* __restrict__ M2) {
    int t = threadIdx.x;
    if (t >= LL * LL) return;
    int l = t / LL, k = t % LL;
    float a = 0.f, b = 0.f;
    for (int m = 0; m < LL; m++) {
        a += C[l * LL + m] * Wsp[m * LL + k];
        b += C[l * LL + m] * Wbi[m * LL + k];
    }
    M1[t] = a; M2[t] = b;
}

// ---------------- initial softmax + zero bi (22 rows: 21 msg + 1 norm)
__global__ void k_sm0(const float* __restrict__ in, float* __restrict__ q,
                      float* __restrict__ bi) {
    int i = blockIdx.x * blockDim.x + threadIdx.x;
    if (i >= NPIX) return;
    float v[LL];
    float m = -1e30f;
    for (int l = 0; l < LL; l++) { v[l] = in[l * NPIX + i]; m = fmaxf(m, v[l]); }
    float s = 0.f;
    for (int l = 0; l < LL; l++) { v[l] = __expf(v[l] - m); s += v[l]; }
    float r = 1.0f / s;
    for (int l = 0; l < LL; l++) {
        q[l * NPIX + i] = v[l] * r;
        bi[l * NPIX + i] = 0.f;
    }
    bi[LL * NPIX + i] = 0.f;   // norm row
}

// ---------------- separable spatial filter (R2 structure: 420-block grids)
__global__ void k_spat_x(const float* __restrict__ q, float* __restrict__ tmpx) {
    __shared__ float g[WW];
    __shared__ float rows[4][WW];
    int l = blockIdx.x;
    int y = blockIdx.y * 4 + threadIdx.y;
    int x = threadIdx.x;
    int t = threadIdx.y * WW + threadIdx.x;
    if (t < WW) g[t] = __expf(-(float)(t * t) * (1.0f / 18.0f));
    rows[threadIdx.y][x] = q[l * NPIX + y * WW + x];
    __syncthreads();
    float s = 0.f;
    for (int xp = 0; xp < WW; xp++) {
        int d = x - xp; d = d < 0 ? -d : d;
        s += g[d] * rows[threadIdx.y][xp];
    }
    tmpx[l * NPIX + y * WW + x] = s;
}

__global__ void k_spat_y(const float* __restrict__ tmpx, float* __restrict__ sp) {
    __shared__ float g[HH];
    int l = blockIdx.x;
    int y = blockIdx.y * 4 + threadIdx.y;
    int x = threadIdx.x;
    int t = threadIdx.y * WW + threadIdx.x;
    if (t < HH) g[t] = __expf(-(float)(t * t) * (1.0f / 18.0f));
    __syncthreads();
    const float* base = tmpx + l * NPIX + x;
    float s = 0.f;
    for (int yp = 0; yp < HH; yp++) {
        int d = y - yp; d = d < 0 ? -d : d;
        s += g[d] * base[yp * WW];
    }
    sp[l * NPIX + y * WW + x] = s;
}

// ---------------- bilateral via chained MFMA.
// mfma1: D1[j,i] = fj·(log2e*fi) with hi/lo k-slot pairing:
//   A [h0..h4, l2,l3,l4, h2,h3,h4, l2,l3,l4, 0,0]
//   B [H0..H4, H2,H3,H4, L2,L3,L4, L2,L3,L4, 0,0]
//   => pos: h·H;  rgb: (h+l)·(H+L) exact
// E = exp2(D1 + mhs_j + mhs_i); mfma2: acc[l,i] += Q^T[l,j-slot]·E[j-slot,i]
// Q row 21 = ones -> acc row 21 = sum_j K (normalizer, free).
__global__ __launch_bounds__(256, 4)
void k_bilat(const float* __restrict__ feat, const float* __restrict__ mhs,
             const ushort* __restrict__ fjg, const float* __restrict__ q,
             float* __restrict__ bi) {
    __shared__ __align__(16) uint  FjL[SJ * 12];    // 48-B rows: 16 bf16 + pad
    __shared__ __align__(16) float mhsL[SJ];
    __shared__ __align__(16) uint  QL[32 * QROW];   // 656-B rows: 320 bf16 + pad
    int tid = threadIdx.x;
    int j0 = blockIdx.y * SJ;
    // ---- stage Fj rows (32 B each -> 48-B LDS rows)
    for (int idx = tid; idx < SJ * 2; idx += 256) {
        int r = idx >> 1, hf = idx & 1;
        uint4 v = ((const uint4*)(fjg + (size_t)(j0 + r) * 16))[hf];
        *(uint4*)&FjL[r * 12 + hf * 4] = v;
    }
    // ---- stage mhs
    for (int idx = tid; idx < SJ; idx += 256) mhsL[idx] = mhs[j0 + idx];
    // ---- stage Q as bf16 [32 l-rows][SJ j] (row21=ones, 22..31=0)
    for (int idx = tid; idx < 32 * (SJ / 2); idx += 256) {
        int l = idx / (SJ / 2), jp = idx % (SJ / 2);
        uint v;
        if (l < LL) {
            const float* p = q + (size_t)l * NPIX + j0 + 2 * jp;
            v = pk2(p[0], p[1]);
        } else {
            v = (l == LL) ? 0x3F803F80u : 0u;
        }
        QL[l * QROW + jp] = v;
    }
    int lane = tid & 63, wid = tid >> 6;
    int h = lane >> 5, m = lane & 31;
    int i = blockIdx.x * 128 + wid * 32 + m;
    // ---- persistent B-operand: this lane's i-features, log2e-scaled, hi/lo
    float a[5];
    ushort Hi[5], Lo[5];
#pragma unroll
    for (int c = 0; c < 5; c++) {
        a[c] = C_LOG2E * feat[c * NPIX + i];
        Hi[c] = bf_rne(a[c]);
        Lo[c] = bf_rne(a[c] - bf_to_f(Hi[c]));
    }
    ushort kv[16];
    kv[0] = Hi[0]; kv[1] = Hi[1]; kv[2] = Hi[2]; kv[3] = Hi[3]; kv[4] = Hi[4];
    kv[5] = Hi[2]; kv[6] = Hi[3]; kv[7] = Hi[4];
    kv[8] = Lo[2]; kv[9] = Lo[3]; kv[10] = Lo[4];
    kv[11] = Lo[2]; kv[12] = Lo[3]; kv[13] = Lo[4];
    kv[14] = 0; kv[15] = 0;
    union U8 { uint u[4]; short8 s; };
    U8 bfr;
#pragma unroll
    for (int t = 0; t < 4; t++)
        bfr.u[t] = (uint)kv[h * 8 + 2 * t] | ((uint)kv[h * 8 + 2 * t + 1] << 16);
    float mi = mhs[i];
    // A-frag row permutation: swap bit2<->bit3 so D1 rows align with mfma2 B k-slots
    int jrow = (m & ~12) | ((m & 4) << 1) | ((m & 8) >> 1);
    __syncthreads();
    f32x16 acc = zero16();
    for (int c = 0; c < CHK; c++) {
        int jb = c * 32;
        short8 af = *(const short8*)&FjL[(jb + jrow) * 12 + h * 4];
        f32x16 d1 = __builtin_amdgcn_mfma_f32_32x32x16_bf16(af, bfr.s, zero16(), 0, 0, 0);
        float4 mja = *(const float4*)&mhsL[jb + 8 * h];
        float4 mjb = *(const float4*)&mhsL[jb + 8 * h + 4];
        float4 mjc = *(const float4*)&mhsL[jb + 16 + 8 * h];
        float4 mjd = *(const float4*)&mhsL[jb + 16 + 8 * h + 4];
        U8 ea, eb;
        ea.u[0] = pk2(exp2f(d1[0]  + mja.x + mi), exp2f(d1[1]  + mja.y + mi));
        ea.u[1] = pk2(exp2f(d1[2]  + mja.z + mi), exp2f(d1[3]  + mja.w + mi));
        ea.u[2] = pk2(exp2f(d1[4]  + mjb.x + mi), exp2f(d1[5]  + mjb.y + mi));
        ea.u[3] = pk2(exp2f(d1[6]  + mjb.z + mi), exp2f(d1[7]  + mjb.w + mi));
        eb.u[0] = pk2(exp2f(d1[8]  + mjc.x + mi), exp2f(d1[9]  + mjc.y + mi));
        eb.u[1] = pk2(exp2f(d1[10] + mjc.z + mi), exp2f(d1[11] + mjc.w + mi));
        eb.u[2] = pk2(exp2f(d1[12] + mjd.x + mi), exp2f(d1[13] + mjd.y + mi));
        eb.u[3] = pk2(exp2f(d1[14] + mjd.z + mi), exp2f(d1[15] + mjd.w + mi));
        const uint* qr = &QL[m * QROW + c * 16 + h * 4];
        short8 qa = *(const short8*)qr;
        short8 qb = *(const short8*)(qr + 8);
        acc = __builtin_amdgcn_mfma_f32_32x32x16_bf16(qa, ea.s, acc, 0, 0, 0);
        acc = __builtin_amdgcn_mfma_f32_32x32x16_bf16(qb, eb.s, acc, 0, 0, 0);
    }
#pragma unroll
    for (int r = 0; r < 16; r++) {
        int l = (r & 3) + 8 * (r >> 2) + 4 * h;
        if (l < LL + 1) atomicAdd(&bi[(size_t)l * NPIX + i], acc[r]);
    }
}

// ---------------- combine (+ fused softmax; norm read from bi row 21)
__global__ void k_comb(const float* __restrict__ unary, const float* __restrict__ sp,
                       float* __restrict__ bi, const float* __restrict__ nsp,
                       const float* __restrict__ M1, const float* __restrict__ M2,
                       float* __restrict__ qout, float* __restrict__ out, int last) {
    __shared__ float m1s[LL * 24];
    __shared__ float m2s[LL * 24];
    int tid = threadIdx.x;
    for (int t = tid; t < LL * LL; t += blockDim.x) {
        int l = t / LL, k = t % LL;
        m1s[l * 24 + k] = M1[t];
        m2s[l * 24 + k] = M2[t];
    }
    __syncthreads();
    int i = blockIdx.x * blockDim.x + tid;
    if (i >= NPIX) return;
    float ns = nsp[i];
    float nb = 1.0f / (bi[LL * NPIX + i] + 1e-8f);
    float sv[LL], bv[LL];
    for (int k = 0; k < LL; k++) {
        sv[k] = sp[k * NPIX + i] * ns;
        bv[k] = bi[k * NPIX + i] * nb;
    }
    float a[LL];
    for (int l = 0; l < LL; l++) {
        float acc = unary[l * NPIX + i];
        const float* r1 = &m1s[l * 24];
        const float* r2 = &m2s[l * 24];
#pragma unroll
        for (int k = 0; k < LL; k++) acc += r1[k] * sv[k] + r2[k] * bv[k];
        a[l] = acc;
    }
    if (last) {
        for (int l = 0; l < LL; l++) out[l * NPIX + i] = a[l];
    } else {
        float m = -1e30f;
        for (int l = 0; l < LL; l++) m = fmaxf(m, a[l]);
        float s = 0.f;
        for (int l = 0; l < LL; l++) { a[l] = __expf(a[l] - m); s += a[l]; }
        float r = 1.0f / s;
        for (int l = 0; l < LL; l++) {
            qout[l * NPIX + i] = a[l] * r;
            bi[l * NPIX + i] = 0.f;
        }
        bi[LL * NPIX + i] = 0.f;
    }
}

extern "C" void kernel_launch(void* const* d_in, const int* in_sizes, int n_in,
                              void* d_out, int out_size, void* d_ws, size_t ws_size,
                              hipStream_t stream) {
    const float* img   = (const float*)d_in[0];
    const float* unary = (const float*)d_in[1];
    const float* Wsp   = (const float*)d_in[2];
    const float* Wbi   = (const float*)d_in[3];
    const float* C     = (const float*)d_in[4];
    float* out = (float*)d_out;

    const int LN = LL * NPIX;
    float* w = (float*)d_ws;
    float*  q    = w;  w += LN;
    float*  tmpx = w;  w += LN;
    float*  sp   = w;  w += LN;
    float*  bi   = w;  w += (LL + 1) * NPIX;     // 21 msg rows + 1 norm row
    float*  feat = w;  w += 5 * NPIX;
    float*  mhs  = w;  w += NPIX;
    float*  nsp  = w;  w += NPIX;
    ushort* fjg  = (ushort*)w;  w += 8 * NPIX;   // [N][16 bf16] = 32 B/row
    float*  M1   = w;  w += LL * LL;
    float*  M2   = w;  w += LL * LL;

    k_pre<<<NPIX / 256, 256, 0, stream>>>(img, feat, fjg, mhs, nsp);
    k_mats<<<1, 512, 0, stream>>>(Wsp, Wbi, C, M1, M2);
    k_sm0<<<NPIX / 256, 256, 0, stream>>>(unary, q, bi);

    for (int it = 0; it < NITER; it++) {
        int last = (it == NITER - 1);
        k_spat_x<<<dim3(LL, HH / 4), dim3(WW, 4), 0, stream>>>(q, tmpx);
        k_spat_y<<<dim3(LL, HH / 4), dim3(WW, 4), 0, stream>>>(tmpx, sp);
        k_bilat<<<dim3(NPIX / 128, NPIX / SJ), 256, 0, stream>>>(feat, mhs, fjg, q, bi);
        k_comb<<<NPIX / 256, 256, 0, stream>>>(unary, sp, bi, nsp, M1, M2, q, out, last);
    }
}